// Round 14
// baseline (224.873 us; speedup 1.0000x reference)
//
#include <hip/hip_runtime.h>
#include <hip/hip_bf16.h>

typedef __hip_bfloat16 bf16_t;
typedef __attribute__((ext_vector_type(8))) short bf16x8;
typedef __attribute__((ext_vector_type(4))) float f32x4;

#define S_LEN   2048
#define D_MODEL 2048
#define N_QH    32
#define N_KVH   8
#define HEAD_D  64
#define KV_D    512
#define M_ROWS  4096
#define QK_SCALE (0.125f * 1.44269504088896340736f)   // att_scale * log2(e), folded into Q
#define NQT     16              // q-tiles of 128 rows

// ---------------- weight transposes + RoPE table, one dispatch ----------------
// grid (161, 64): x<160 -> weight transpose tiles; x==160 -> RoPE table slice y.
__global__ void wt_conv_all_kernel(const float* __restrict__ wq, const float* __restrict__ wk,
                                   const float* __restrict__ wv, const float* __restrict__ wo,
                                   bf16_t* __restrict__ tq, bf16_t* __restrict__ tk,
                                   bf16_t* __restrict__ tv, bf16_t* __restrict__ to,
                                   float* __restrict__ cosT, float* __restrict__ sinT) {
    const int x = blockIdx.x;
    if (x == 160) {
        // RoPE: 64 y-blocks x 32 pos each; 256 threads = 8 pos x 32 j per pass
        int j = threadIdx.x & 31;
        double invf = pow(10000.0, -(double)(2 * j) / 64.0);
#pragma unroll
        for (int i = 0; i < 4; i++) {
            int pos = blockIdx.y * 32 + i * 8 + (threadIdx.x >> 5);
            double a = (double)pos * invf;
            cosT[pos * 32 + j] = (float)cos(a);
            sinT[pos * 32 + j] = (float)sin(a);
        }
        return;
    }
    __shared__ float tile[32][33];
    const float* W; bf16_t* Wt; int N, nb;
    if (x < 64)       { W = wq; Wt = tq; N = D_MODEL; nb = x; }
    else if (x < 80)  { W = wk; Wt = tk; N = KV_D;    nb = x - 64; }
    else if (x < 96)  { W = wv; Wt = tv; N = KV_D;    nb = x - 80; }
    else              { W = wo; Wt = to; N = D_MODEL; nb = x - 96; }
    const int K = D_MODEL;
    int n0 = nb * 32, k0 = blockIdx.y * 32;
    int tx = threadIdx.x & 31, ty = threadIdx.x >> 5;   // 32 x 8
#pragma unroll
    for (int i = 0; i < 4; i++) {
        int r = ty + i * 8;
        tile[r][tx] = W[(size_t)(k0 + r) * N + n0 + tx];
    }
    __syncthreads();
#pragma unroll
    for (int i = 0; i < 4; i++) {
        int r = ty + i * 8;
        Wt[(size_t)(n0 + r) * K + k0 + tx] = __float2bfloat16(tile[tx][r]);
    }
}

struct __align__(8) bf16x4s { bf16_t x, y, z, w; };

// ---------------- async 16B global->LDS ----------------
__device__ __forceinline__ void async_copy16(const bf16_t* g, bf16_t* l) {
    __builtin_amdgcn_global_load_lds((const __attribute__((address_space(1))) void*)g,
                                     (__attribute__((address_space(3))) void*)l, 16, 0, 0);
}

// ---------------- GEMM: 128x128, BK=64, swizzled; 1D grid with XCD-tiled decode ----------------
template <int ROPE, int OUTF32, int QSCALE>
__global__ __launch_bounds__(256, 2)
void gqa_gemm_kernel(const bf16_t* __restrict__ A, const bf16_t* __restrict__ Bt,
                     const float* __restrict__ bias, void* __restrict__ Cout,
                     int M, int N, int K,
                     const float* __restrict__ cosT, const float* __restrict__ sinT) {
    __shared__ __align__(16) bf16_t As[128 * 64];
    __shared__ __align__(16) bf16_t Bs[128 * 64];

    const int t = threadIdx.x;
    const int bx = blockIdx.x;
    const int xcd = bx & 7, j = bx >> 3;               // j: 0..63
    const int am0 = (((xcd >> 1) << 3) + (j >> 3)) * 128;
    const int bn0 = (((xcd & 1) << 3) + (j & 7)) * 128;

    const int l = t & 63, w = t >> 6;
    const int wr = w >> 1, wc = w & 1;
    const int lr = l & 15, lk = l >> 4;

    f32x4 acc[4][4];
#pragma unroll
    for (int i = 0; i < 4; i++)
#pragma unroll
        for (int jx = 0; jx < 4; jx++) acc[i][jx] = (f32x4)0.0f;

    const int r0 = t >> 3;                  // 0..31
    const int c  = (t & 7) ^ (r0 & 7);      // pre-swizzled source chunk
    const bf16_t* aptr = A + (size_t)(am0 + r0) * K + c * 8;
    const bf16_t* bptr = Bt + (size_t)(bn0 + r0) * K + c * 8;
    bf16_t* aLds = As + r0 * 64 + (t & 7) * 8;
    bf16_t* bLds = Bs + r0 * 64 + (t & 7) * 8;

    for (int k0 = 0; k0 < K; k0 += 64) {
#pragma unroll
        for (int s = 0; s < 4; ++s) {
            async_copy16(aptr + (size_t)(s * 32) * K + k0, aLds + s * 2048);
            async_copy16(bptr + (size_t)(s * 32) * K + k0, bLds + s * 2048);
        }
        __syncthreads();

        bf16x8 af[4][2], bfr[4][2];
#pragma unroll
        for (int mi = 0; mi < 4; mi++)
#pragma unroll
            for (int ks = 0; ks < 2; ks++)
                af[mi][ks] = *(const bf16x8*)&As[(wr * 64 + mi * 16 + lr) * 64 +
                                 ((ks * 32 + lk * 8) ^ ((lr & 7) << 3))];
#pragma unroll
        for (int ni = 0; ni < 4; ni++)
#pragma unroll
            for (int ks = 0; ks < 2; ks++)
                bfr[ni][ks] = *(const bf16x8*)&Bs[(wc * 64 + ni * 16 + lr) * 64 +
                                  ((ks * 32 + lk * 8) ^ ((lr & 7) << 3))];
#pragma unroll
        for (int mi = 0; mi < 4; mi++)
#pragma unroll
            for (int ni = 0; ni < 4; ni++)
#pragma unroll
                for (int ks = 0; ks < 2; ks++)
                    acc[mi][ni] = __builtin_amdgcn_mfma_f32_16x16x32_bf16(
                        af[mi][ks], bfr[ni][ks], acc[mi][ni], 0, 0, 0);
        __syncthreads();
    }

#pragma unroll
    for (int mi = 0; mi < 4; mi++) {
#pragma unroll
        for (int reg = 0; reg < 4; reg++) {
            int row = am0 + wr * 64 + mi * 16 + lk * 4 + reg;
            if (OUTF32) {
                float* out = (float*)Cout;
#pragma unroll
                for (int ni = 0; ni < 4; ni++) {
                    int col = bn0 + wc * 64 + ni * 16 + lr;
                    out[(size_t)row * N + col] = acc[mi][ni][reg] + bias[col];
                }
            } else if (ROPE) {
                bf16_t* out = (bf16_t*)Cout;
                int pos = row & (S_LEN - 1);
#pragma unroll
                for (int np = 0; np < 2; np++) {
                    int jj = np * 16 + lr;
                    float cs = cosT[pos * 32 + jj];
                    float sn = sinT[pos * 32 + jj];
                    int col1 = bn0 + wc * 64 + np * 16 + lr;
                    float x1 = acc[mi][np][reg] + bias[col1];
                    float x2 = acc[mi][np + 2][reg] + bias[col1 + 32];
                    float o1 = x1 * cs - x2 * sn;
                    float o2 = x2 * cs + x1 * sn;
                    if (QSCALE) { o1 *= QK_SCALE; o2 *= QK_SCALE; }
                    out[(size_t)row * N + col1]      = __float2bfloat16(o1);
                    out[(size_t)row * N + col1 + 32] = __float2bfloat16(o2);
                }
            } else {
                bf16_t* out = (bf16_t*)Cout;
#pragma unroll
                for (int ni = 0; ni < 4; ni++) {
                    int col = bn0 + wc * 64 + ni * 16 + lr;
                    out[(size_t)row * N + col] =
                        __float2bfloat16(acc[mi][ni][reg] + bias[col]);
                }
            }
        }
    }
}

// ---------------- fused K+V+Q projection kernel (all fp32-A reg-staged, pipelined) ----------------
// grid 2048: blocks 0..1023 = K/V proj (round-13 structure); 1024..2047 = Q proj
// (BM=64 x BN=128, +RoPE +QK_SCALE). Counted vmcnt(2) keeps A-prefetch in flight.
__global__ __launch_bounds__(256, 4)
void gqa_kvq_kernel(const float* __restrict__ Key, const float* __restrict__ Val,
                    const float* __restrict__ Query,
                    const bf16_t* __restrict__ Wtk, const bf16_t* __restrict__ Wtv,
                    const bf16_t* __restrict__ Wtq,
                    const float* __restrict__ bk, const float* __restrict__ bv,
                    const float* __restrict__ bq,
                    bf16_t* __restrict__ Kout, bf16_t* __restrict__ VtOut,
                    bf16_t* __restrict__ Qout,
                    const float* __restrict__ cosT, const float* __restrict__ sinT) {
    __shared__ __align__(16) char smem[12288];
    bf16_t* As  = (bf16_t*)smem;                 // [64][32] = 4096 B
    bf16_t* Bs  = (bf16_t*)(smem + 4096);        // kv: [64][32]; q: [128][32] = 8192 B
    bf16_t* VtE = (bf16_t*)smem;                 // [64][72] = 9216 B (kv post-loop)

    const int bx = blockIdx.x;
    const int t = threadIdx.x;
    const int l = t & 63, w = t >> 6;
    const int lr = l & 15, lk = l >> 4;
    const int sr = t >> 2;              // 0..63
    const int sc = (t & 3) * 8;
    constexpr int K = D_MODEL;

    if (bx >= 1024) {
        // ================= Q projection: 64 x 128 tile =================
        const int qbx = bx - 1024;
        const int xcd = qbx & 7;
        const int j   = qbx >> 3;                 // 0..127
        const int am0 = ((xcd << 3) + (j & 7)) * 64;   // am fastest within xcd
        const int bn0 = (j >> 3) * 128;

        f32x4 acc[8];
#pragma unroll
        for (int jx = 0; jx < 8; jx++) acc[jx] = (f32x4)0.0f;

        const float*  aptr = Query + (size_t)(am0 + sr) * K + sc;
        const bf16_t* bptr = Wtq + (size_t)(bn0 + sr) * K + sc;
        bf16_t* aLds  = As + sr * 32 + sc;
        bf16_t* bLds  = Bs + t * 8;

        float4 pa0 = ((const float4*)aptr)[0];
        float4 pa1 = ((const float4*)aptr)[1];

        for (int it = 0; it < K / 32; ++it) {
            union { bf16x8 v; bf16_t e[8]; } u;
            u.e[0] = __float2bfloat16(pa0.x); u.e[1] = __float2bfloat16(pa0.y);
            u.e[2] = __float2bfloat16(pa0.z); u.e[3] = __float2bfloat16(pa0.w);
            u.e[4] = __float2bfloat16(pa1.x); u.e[5] = __float2bfloat16(pa1.y);
            u.e[6] = __float2bfloat16(pa1.z); u.e[7] = __float2bfloat16(pa1.w);
            *(bf16x8*)aLds = u.v;
            async_copy16(bptr + it * 32, bLds);                          // B rows 0-63
            async_copy16(bptr + (size_t)64 * K + it * 32, bLds + 2048);  // B rows 64-127
            __builtin_amdgcn_sched_barrier(0);
            if (it + 1 < K / 32) {
                const float* ap = aptr + (it + 1) * 32;
                pa0 = ((const float4*)ap)[0];
                pa1 = ((const float4*)ap)[1];
                __builtin_amdgcn_sched_barrier(0);
                asm volatile("s_waitcnt lgkmcnt(0) vmcnt(2)" ::: "memory");
            } else {
                asm volatile("s_waitcnt lgkmcnt(0) vmcnt(0)" ::: "memory");
            }
            __builtin_amdgcn_sched_barrier(0);
            __builtin_amdgcn_s_barrier();
            __builtin_amdgcn_sched_barrier(0);

            bf16x8 af = *(const bf16x8*)&As[(w * 16 + lr) * 32 + lk * 8];
#pragma unroll
            for (int ni = 0; ni < 8; ni++) {
                bf16x8 bfr = *(const bf16x8*)&Bs[(ni * 16 + lr) * 32 + lk * 8];
                acc[ni] = __builtin_amdgcn_mfma_f32_16x16x32_bf16(af, bfr, acc[ni], 0, 0, 0);
            }
            __builtin_amdgcn_sched_barrier(0);
            __builtin_amdgcn_s_barrier();
            __builtin_amdgcn_sched_barrier(0);
        }

        // RoPE + QK_SCALE epilogue; cols span 2 heads of 64
#pragma unroll
        for (int reg = 0; reg < 4; reg++) {
            int row = am0 + w * 16 + lk * 4 + reg;
            int pos = row & (S_LEN - 1);
#pragma unroll
            for (int hg = 0; hg < 2; hg++)
#pragma unroll
                for (int np = 0; np < 2; np++) {
                    int jj = np * 16 + lr;
                    float cs = cosT[pos * 32 + jj];
                    float sn = sinT[pos * 32 + jj];
                    int col1 = bn0 + hg * 64 + np * 16 + lr;
                    float x1 = acc[hg * 4 + np][reg] + bq[col1];
                    float x2 = acc[hg * 4 + np + 2][reg] + bq[col1 + 32];
                    Qout[(size_t)row * D_MODEL + col1] =
                        __float2bfloat16((x1 * cs - x2 * sn) * QK_SCALE);
                    Qout[(size_t)row * D_MODEL + col1 + 32] =
                        __float2bfloat16((x2 * cs + x1 * sn) * QK_SCALE);
                }
        }
        return;
    }

    // ================= K / V projection: 64 x 64 tile (round-13) =================
    const int xcd = bx & 7;
    const int j   = bx >> 3;               // 0..127
    const int z   = xcd >> 2;
    const int am0 = (((xcd & 3) << 4) + (j >> 3)) * 64;
    const int bn0 = (j & 7) * 64;

    const float* A32  = z ? Val : Key;
    const bf16_t* Bt  = z ? Wtv : Wtk;
    const float* bias = z ? bv : bk;

    f32x4 acc[4];
#pragma unroll
    for (int jx = 0; jx < 4; jx++) acc[jx] = (f32x4)0.0f;

    const float*  aptr = A32 + (size_t)(am0 + sr) * K + sc;
    const bf16_t* bptr = Bt + (size_t)(bn0 + sr) * K + sc;
    bf16_t* aLds = As + sr * 32 + sc;
    bf16_t* bLds = Bs + t * 8;

    float4 pa0 = ((const float4*)aptr)[0];
    float4 pa1 = ((const float4*)aptr)[1];

    for (int it = 0; it < K / 32; ++it) {
        union { bf16x8 v; bf16_t e[8]; } u;
        u.e[0] = __float2bfloat16(pa0.x); u.e[1] = __float2bfloat16(pa0.y);
        u.e[2] = __float2bfloat16(pa0.z); u.e[3] = __float2bfloat16(pa0.w);
        u.e[4] = __float2bfloat16(pa1.x); u.e[5] = __float2bfloat16(pa1.y);
        u.e[6] = __float2bfloat16(pa1.z); u.e[7] = __float2bfloat16(pa1.w);
        *(bf16x8*)aLds = u.v;
        async_copy16(bptr + it * 32, bLds);
        __builtin_amdgcn_sched_barrier(0);
        if (it + 1 < K / 32) {
            const float* ap = aptr + (it + 1) * 32;
            pa0 = ((const float4*)ap)[0];
            pa1 = ((const float4*)ap)[1];
            __builtin_amdgcn_sched_barrier(0);
            asm volatile("s_waitcnt lgkmcnt(0) vmcnt(2)" ::: "memory");
        } else {
            asm volatile("s_waitcnt lgkmcnt(0) vmcnt(0)" ::: "memory");
        }
        __builtin_amdgcn_sched_barrier(0);
        __builtin_amdgcn_s_barrier();
        __builtin_amdgcn_sched_barrier(0);

        bf16x8 af = *(const bf16x8*)&As[(w * 16 + lr) * 32 + lk * 8];
#pragma unroll
        for (int ni = 0; ni < 4; ni++) {
            bf16x8 bfr = *(const bf16x8*)&Bs[(ni * 16 + lr) * 32 + lk * 8];
            acc[ni] = __builtin_amdgcn_mfma_f32_16x16x32_bf16(af, bfr, acc[ni], 0, 0, 0);
        }
        __builtin_amdgcn_sched_barrier(0);
        __builtin_amdgcn_s_barrier();
        __builtin_amdgcn_sched_barrier(0);
    }

    if (z == 0) {
        // K projection: RoPE epilogue, row-major kb[M][KV_D]
#pragma unroll
        for (int reg = 0; reg < 4; reg++) {
            int row = am0 + w * 16 + lk * 4 + reg;
            int pos = row & (S_LEN - 1);
#pragma unroll
            for (int np = 0; np < 2; np++) {
                int jj = np * 16 + lr;
                float cs = cosT[pos * 32 + jj];
                float sn = sinT[pos * 32 + jj];
                int col1 = bn0 + np * 16 + lr;
                float x1 = acc[np][reg] + bias[col1];
                float x2 = acc[np + 2][reg] + bias[col1 + 32];
                Kout[(size_t)row * KV_D + col1]      = __float2bfloat16(x1 * cs - x2 * sn);
                Kout[(size_t)row * KV_D + col1 + 32] = __float2bfloat16(x2 * cs + x1 * sn);
            }
        }
    } else {
        // V projection: transpose via bf16 LDS tile [64 d][72]
        __syncthreads();
#pragma unroll
        for (int ni = 0; ni < 4; ni++) {
            bf16x4s pk;
            pk.x = __float2bfloat16(acc[ni][0] + bias[bn0 + ni * 16 + lr]);
            pk.y = __float2bfloat16(acc[ni][1] + bias[bn0 + ni * 16 + lr]);
            pk.z = __float2bfloat16(acc[ni][2] + bias[bn0 + ni * 16 + lr]);
            pk.w = __float2bfloat16(acc[ni][3] + bias[bn0 + ni * 16 + lr]);
            *(bf16x4s*)&VtE[(ni * 16 + lr) * 72 + w * 16 + lk * 4] = pk;
        }
        __syncthreads();
        const int d = t & 63, w2 = t >> 6;
        const int bI = am0 >> 11;
        const int kvhI = bn0 >> 6;
        const int sl = (am0 & (S_LEN - 1)) + w2 * 16;
        bf16_t* dst = VtOut + ((size_t)(bI * N_KVH + kvhI) * HEAD_D + d) * S_LEN + sl;
        const bf16_t* src = &VtE[d * 72 + w2 * 16];
        *(bf16x8*)dst       = *(const bf16x8*)src;
        *(bf16x8*)(dst + 8) = *(const bf16x8*)(src + 8);
    }
}

// ---------------- staging (512 threads: one 16B async copy per thread) ----------------
__device__ __forceinline__ void stage_K8(const bf16_t* KB, bf16_t* dst, int kt, int t) {
    const int skey = t >> 3;                // 0..63
    const int c    = (t & 7) ^ (skey & 7);  // source chunk
    async_copy16(KB + (size_t)(kt * 64 + skey) * KV_D + c * 8, dst + t * 8);
}
__device__ __forceinline__ void stage_V8(const bf16_t* VTb, bf16_t* dst, int kt, int t) {
    const int sd = t >> 3;                  // 0..63
    const int c  = (t & 7) ^ (sd & 7);      // source chunk
    async_copy16(VTb + (size_t)sd * S_LEN + kt * 64 + c * 8, dst + t * 8);
}

// ---------------- causal GQA flash attention (swapped-QK^T, 8 waves) ----------------
// Fixed-shift softmax; denominator computed on the MFMA pipe via ones-row:
// oaccS = mfma(ones, P^T) accumulates l[q] (replaces VALU adds + shuffles).
__global__ __launch_bounds__(512, 4)
void gqa_attn_kernel(const bf16_t* __restrict__ Q, const bf16_t* __restrict__ Kb,
                     const bf16_t* __restrict__ VT, bf16_t* __restrict__ Ctx) {
    __shared__ __align__(16) bf16_t Ks[2][64 * 64];    // [key][d], source-swizzled
    __shared__ __align__(16) bf16_t Vs[2][64 * 64];    // [d][key], source-swizzled
    __shared__ __align__(16) bf16_t Pw[8][16 * 72];    // per-wave P [q][key]

    const int t = threadIdx.x, l = t & 63, w = t >> 6;   // w = 0..7
    const int lr = l & 15, lk = l >> 4;

    const int flat = blockIdx.x;
    const int xcd = flat & 7, j0 = flat >> 3;            // j0: 0..63
    const int combo  = xcd * 2 + (j0 >> 5);              // b*8+kvh (16 combos)
    const int within = j0 & 31;                          // 4 heads x 8 pairs
    const int b   = combo >> 3;
    const int kvh = combo & 7;
    const int h   = kvh * 4 + (within >> 3);
    const int p   = within & 7;

    bf16x8 vones;
#pragma unroll
    for (int i = 0; i < 8; i++) vones[i] = (short)0x3F80;   // bf16 1.0

    const bf16_t* KB  = Kb + (size_t)b * S_LEN * KV_D + kvh * HEAD_D;
    const bf16_t* VTb = VT + ((size_t)(b * N_KVH + kvh) * HEAD_D) * S_LEN;

#pragma unroll
    for (int half = 0; half < 2; ++half) {
        const int qt  = half ? (NQT - 1 - p) : p;
        const int q0w = qt * 128 + w * 16;
        const int qg  = q0w + lr;                       // this lane's q row

        bf16x8 qf[2];
        {
            const bf16_t* qrow = Q + ((size_t)(b * S_LEN + qg)) * D_MODEL + h * HEAD_D;
            qf[0] = *(const bf16x8*)(qrow + lk * 8);
            qf[1] = *(const bf16x8*)(qrow + 32 + lk * 8);
        }

        f32x4 oaccT[4];                                 // O^T: d = df*16+lk*4+r, q = lr
        f32x4 oaccS = (f32x4)0.0f;                      // denominator rows (all equal)
#pragma unroll
        for (int df = 0; df < 4; df++) oaccT[df] = (f32x4)0.0f;

        const int nkt = 2 * qt + 2;

        stage_K8(KB, Ks[0], 0, t);
        stage_V8(VTb, Vs[0], 0, t);
        __syncthreads();

        int cur = 0;
        for (int kt = 0; kt < nkt; ++kt) {
            const bool pre = (kt + 1 < nkt);
            if (pre) {
                stage_K8(KB, Ks[cur ^ 1], kt + 1, t);
                stage_V8(VTb, Vs[cur ^ 1], kt + 1, t);
            }

            if (kt * 64 <= q0w + 15) {                  // wave-uniform causal skip
                const bool diag = (kt * 64 + 63 > q0w);

                // ---- S^T = mfma(K, Q): keys in rows, q in cols (pre-scaled) ----
                f32x4 sfrT[4];
#pragma unroll
                for (int ni = 0; ni < 4; ni++) sfrT[ni] = (f32x4)0.0f;
                __builtin_amdgcn_s_setprio(1);
#pragma unroll
                for (int ni = 0; ni < 4; ni++)
#pragma unroll
                    for (int ks = 0; ks < 2; ks++) {
                        bf16x8 kf = *(const bf16x8*)&Ks[cur][(ni * 16 + lr) * 64 +
                                        ((ks * 32 + lk * 8) ^ ((lr & 7) << 3))];
                        sfrT[ni] = __builtin_amdgcn_mfma_f32_16x16x32_bf16(kf, qf[ks],
                                                                           sfrT[ni], 0, 0, 0);
                    }
                __builtin_amdgcn_s_setprio(0);

                // ---- mask + direct exp2 (no max tracking; shift cancels in O/l) ----
#pragma unroll
                for (int ni = 0; ni < 4; ni++) {
                    float e0, e1, e2, e3;
                    {
                        float sc0 = sfrT[ni][0], sc1 = sfrT[ni][1];
                        float sc2 = sfrT[ni][2], sc3 = sfrT[ni][3];
                        if (diag) {
                            int kbase = kt * 64 + ni * 16 + lk * 4;
                            if (kbase + 0 > qg) sc0 = -1e30f;
                            if (kbase + 1 > qg) sc1 = -1e30f;
                            if (kbase + 2 > qg) sc2 = -1e30f;
                            if (kbase + 3 > qg) sc3 = -1e30f;
                        }
                        e0 = exp2f(sc0); e1 = exp2f(sc1);
                        e2 = exp2f(sc2); e3 = exp2f(sc3);
                    }
                    bf16x4s pk;
                    pk.x = __float2bfloat16(e0);
                    pk.y = __float2bfloat16(e1);
                    pk.z = __float2bfloat16(e2);
                    pk.w = __float2bfloat16(e3);
                    *(bf16x4s*)&Pw[w][lr * 72 + ni * 16 + lk * 4] = pk;
                }

                // ---- O^T += mfma(V^T, P^T); l += mfma(ones, P^T) ----
                __builtin_amdgcn_s_setprio(1);
#pragma unroll
                for (int ks = 0; ks < 2; ks++) {
                    bf16x8 pf = *(const bf16x8*)&Pw[w][lr * 72 + ks * 32 + lk * 8];
                    oaccS = __builtin_amdgcn_mfma_f32_16x16x32_bf16(vones, pf, oaccS, 0, 0, 0);
#pragma unroll
                    for (int df = 0; df < 4; df++) {
                        bf16x8 vf = *(const bf16x8*)&Vs[cur][(df * 16 + lr) * 64 +
                                        ((ks * 32 + lk * 8) ^ ((lr & 7) << 3))];
                        oaccT[df] = __builtin_amdgcn_mfma_f32_16x16x32_bf16(vf, pf,
                                            oaccT[df], 0, 0, 0);
                    }
                }
                __builtin_amdgcn_s_setprio(0);
            }

            __syncthreads();
            cur ^= 1;
        }

        // ---- normalize + write ctx (lane owns q = qg; l = oaccS[0]) ----
        {
            float inv = 1.0f / oaccS[0];
            bf16_t* crow = Ctx + ((size_t)(b * S_LEN + qg)) * D_MODEL + h * HEAD_D;
#pragma unroll
            for (int df = 0; df < 4; df++) {
                bf16x4s ov;
                ov.x = __float2bfloat16(oaccT[df][0] * inv);
                ov.y = __float2bfloat16(oaccT[df][1] * inv);
                ov.z = __float2bfloat16(oaccT[df][2] * inv);
                ov.w = __float2bfloat16(oaccT[df][3] * inv);
                *(bf16x4s*)(crow + df * 16 + lk * 4) = ov;
            }
        }
    }
}

extern "C" void kernel_launch(void* const* d_in, const int* in_sizes, int n_in,
                              void* d_out, int out_size, void* d_ws, size_t ws_size,
                              hipStream_t stream) {
    const float* query = (const float*)d_in[0];
    const float* key_  = (const float*)d_in[1];
    const float* value = (const float*)d_in[2];
    const float* w_q = (const float*)d_in[3];
    const float* b_q = (const float*)d_in[4];
    const float* w_k = (const float*)d_in[5];
    const float* b_k = (const float*)d_in[6];
    const float* w_v = (const float*)d_in[7];
    const float* b_v = (const float*)d_in[8];
    const float* w_o = (const float*)d_in[9];
    const float* b_o = (const float*)d_in[10];
    float* out = (float*)d_out;

    char* ws = (char*)d_ws;
    bf16_t* Abuf = (bf16_t*)(ws);                       // 16MB (ctx buffer)
    bf16_t* qb   = (bf16_t*)(ws + (size_t)(16 << 20));  // 16MB
    bf16_t* kb   = (bf16_t*)(ws + (size_t)(32 << 20));  // 4MB
    bf16_t* vt   = (bf16_t*)(ws + (size_t)(36 << 20));  // 4MB (transposed V)
    bf16_t* wtq  = (bf16_t*)(ws + (size_t)(40 << 20));  // 8MB
    bf16_t* wtk  = (bf16_t*)(ws + (size_t)(48 << 20));  // 2MB
    bf16_t* wtv  = (bf16_t*)(ws + (size_t)(50 << 20));  // 2MB
    bf16_t* wto  = (bf16_t*)(ws + (size_t)(52 << 20));  // 8MB
    float* cosT  = (float*)(ws + (size_t)(60 << 20));   // 256KB
    float* sinT  = (float*)(ws + (size_t)(60 << 20) + (256 << 10));

    // weight transposes + RoPE table, one dispatch
    wt_conv_all_kernel<<<dim3(161, 64), 256, 0, stream>>>(w_q, w_k, w_v, w_o,
                                                          wtq, wtk, wtv, wto, cosT, sinT);

    // K + V + Q projections, one dispatch (all read fp32 activations directly)
    gqa_kvq_kernel<<<2048, 256, 0, stream>>>(key_, value, query, wtk, wtv, wtq,
                                             b_k, b_v, b_q, kb, vt, qb, cosT, sinT);

    // Attention -> ctx (Abuf); 8-wave blocks, XCD decode, MFMA-denominator softmax
    gqa_attn_kernel<<<512, 512, 0, stream>>>(qb, kb, vt, Abuf);

    // Output projection -> fp32 d_out: 1D XCD-tiled grid
    gqa_gemm_kernel<0, 1, 0><<<512, 256, 0, stream>>>(
        Abuf, wto, b_o, out, M_ROWS, D_MODEL, D_MODEL, cosT, sinT);
}

// Round 15
// 211.194 us; speedup vs baseline: 1.0648x; 1.0648x over previous
//
#include <hip/hip_runtime.h>
#include <hip/hip_bf16.h>

typedef __hip_bfloat16 bf16_t;
typedef __attribute__((ext_vector_type(8))) short bf16x8;
typedef __attribute__((ext_vector_type(4))) float f32x4;

#define S_LEN   2048
#define D_MODEL 2048
#define N_QH    32
#define N_KVH   8
#define HEAD_D  64
#define KV_D    512
#define M_ROWS  4096
#define QK_SCALE (0.125f * 1.44269504088896340736f)   // att_scale * log2(e), folded into Q
#define NQT     16              // q-tiles of 128 rows

// ---------------- weight transposes + RoPE table, one dispatch ----------------
__global__ void wt_conv_all_kernel(const float* __restrict__ wq, const float* __restrict__ wk,
                                   const float* __restrict__ wv, const float* __restrict__ wo,
                                   bf16_t* __restrict__ tq, bf16_t* __restrict__ tk,
                                   bf16_t* __restrict__ tv, bf16_t* __restrict__ to,
                                   float* __restrict__ cosT, float* __restrict__ sinT) {
    const int x = blockIdx.x;
    if (x == 160) {
        int j = threadIdx.x & 31;
        double invf = pow(10000.0, -(double)(2 * j) / 64.0);
#pragma unroll
        for (int i = 0; i < 4; i++) {
            int pos = blockIdx.y * 32 + i * 8 + (threadIdx.x >> 5);
            double a = (double)pos * invf;
            cosT[pos * 32 + j] = (float)cos(a);
            sinT[pos * 32 + j] = (float)sin(a);
        }
        return;
    }
    __shared__ float tile[32][33];
    const float* W; bf16_t* Wt; int N, nb;
    if (x < 64)       { W = wq; Wt = tq; N = D_MODEL; nb = x; }
    else if (x < 80)  { W = wk; Wt = tk; N = KV_D;    nb = x - 64; }
    else if (x < 96)  { W = wv; Wt = tv; N = KV_D;    nb = x - 80; }
    else              { W = wo; Wt = to; N = D_MODEL; nb = x - 96; }
    const int K = D_MODEL;
    int n0 = nb * 32, k0 = blockIdx.y * 32;
    int tx = threadIdx.x & 31, ty = threadIdx.x >> 5;   // 32 x 8
#pragma unroll
    for (int i = 0; i < 4; i++) {
        int r = ty + i * 8;
        tile[r][tx] = W[(size_t)(k0 + r) * N + n0 + tx];
    }
    __syncthreads();
#pragma unroll
    for (int i = 0; i < 4; i++) {
        int r = ty + i * 8;
        Wt[(size_t)(n0 + r) * K + k0 + tx] = __float2bfloat16(tile[tx][r]);
    }
}

struct __align__(8) bf16x4s { bf16_t x, y, z, w; };

// ---------------- async 16B global->LDS ----------------
__device__ __forceinline__ void async_copy16(const bf16_t* g, bf16_t* l) {
    __builtin_amdgcn_global_load_lds((const __attribute__((address_space(1))) void*)g,
                                     (__attribute__((address_space(3))) void*)l, 16, 0, 0);
}

// ---------------- GEMM: 128x128, BK=64, swizzled; 1D grid with XCD-tiled decode ----------------
template <int ROPE, int OUTF32, int QSCALE>
__global__ __launch_bounds__(256, 2)
void gqa_gemm_kernel(const bf16_t* __restrict__ A, const bf16_t* __restrict__ Bt,
                     const float* __restrict__ bias, void* __restrict__ Cout,
                     int M, int N, int K,
                     const float* __restrict__ cosT, const float* __restrict__ sinT) {
    __shared__ __align__(16) bf16_t As[128 * 64];
    __shared__ __align__(16) bf16_t Bs[128 * 64];

    const int t = threadIdx.x;
    const int bx = blockIdx.x;
    const int xcd = bx & 7, j = bx >> 3;               // j: 0..63
    const int am0 = (((xcd >> 1) << 3) + (j >> 3)) * 128;
    const int bn0 = (((xcd & 1) << 3) + (j & 7)) * 128;

    const int l = t & 63, w = t >> 6;
    const int wr = w >> 1, wc = w & 1;
    const int lr = l & 15, lk = l >> 4;

    f32x4 acc[4][4];
#pragma unroll
    for (int i = 0; i < 4; i++)
#pragma unroll
        for (int jx = 0; jx < 4; jx++) acc[i][jx] = (f32x4)0.0f;

    const int r0 = t >> 3;                  // 0..31
    const int c  = (t & 7) ^ (r0 & 7);      // pre-swizzled source chunk
    const bf16_t* aptr = A + (size_t)(am0 + r0) * K + c * 8;
    const bf16_t* bptr = Bt + (size_t)(bn0 + r0) * K + c * 8;
    bf16_t* aLds = As + r0 * 64 + (t & 7) * 8;
    bf16_t* bLds = Bs + r0 * 64 + (t & 7) * 8;

    for (int k0 = 0; k0 < K; k0 += 64) {
#pragma unroll
        for (int s = 0; s < 4; ++s) {
            async_copy16(aptr + (size_t)(s * 32) * K + k0, aLds + s * 2048);
            async_copy16(bptr + (size_t)(s * 32) * K + k0, bLds + s * 2048);
        }
        __syncthreads();

        bf16x8 af[4][2], bfr[4][2];
#pragma unroll
        for (int mi = 0; mi < 4; mi++)
#pragma unroll
            for (int ks = 0; ks < 2; ks++)
                af[mi][ks] = *(const bf16x8*)&As[(wr * 64 + mi * 16 + lr) * 64 +
                                 ((ks * 32 + lk * 8) ^ ((lr & 7) << 3))];
#pragma unroll
        for (int ni = 0; ni < 4; ni++)
#pragma unroll
            for (int ks = 0; ks < 2; ks++)
                bfr[ni][ks] = *(const bf16x8*)&Bs[(wc * 64 + ni * 16 + lr) * 64 +
                                  ((ks * 32 + lk * 8) ^ ((lr & 7) << 3))];
#pragma unroll
        for (int mi = 0; mi < 4; mi++)
#pragma unroll
            for (int ni = 0; ni < 4; ni++)
#pragma unroll
                for (int ks = 0; ks < 2; ks++)
                    acc[mi][ni] = __builtin_amdgcn_mfma_f32_16x16x32_bf16(
                        af[mi][ks], bfr[ni][ks], acc[mi][ni], 0, 0, 0);
        __syncthreads();
    }

#pragma unroll
    for (int mi = 0; mi < 4; mi++) {
#pragma unroll
        for (int reg = 0; reg < 4; reg++) {
            int row = am0 + wr * 64 + mi * 16 + lk * 4 + reg;
            if (OUTF32) {
                float* out = (float*)Cout;
#pragma unroll
                for (int ni = 0; ni < 4; ni++) {
                    int col = bn0 + wc * 64 + ni * 16 + lr;
                    out[(size_t)row * N + col] = acc[mi][ni][reg] + bias[col];
                }
            } else if (ROPE) {
                bf16_t* out = (bf16_t*)Cout;
                int pos = row & (S_LEN - 1);
#pragma unroll
                for (int np = 0; np < 2; np++) {
                    int jj = np * 16 + lr;
                    float cs = cosT[pos * 32 + jj];
                    float sn = sinT[pos * 32 + jj];
                    int col1 = bn0 + wc * 64 + np * 16 + lr;
                    float x1 = acc[mi][np][reg] + bias[col1];
                    float x2 = acc[mi][np + 2][reg] + bias[col1 + 32];
                    float o1 = x1 * cs - x2 * sn;
                    float o2 = x2 * cs + x1 * sn;
                    if (QSCALE) { o1 *= QK_SCALE; o2 *= QK_SCALE; }
                    out[(size_t)row * N + col1]      = __float2bfloat16(o1);
                    out[(size_t)row * N + col1 + 32] = __float2bfloat16(o2);
                }
            } else {
                bf16_t* out = (bf16_t*)Cout;
#pragma unroll
                for (int ni = 0; ni < 4; ni++) {
                    int col = bn0 + wc * 64 + ni * 16 + lr;
                    out[(size_t)row * N + col] =
                        __float2bfloat16(acc[mi][ni][reg] + bias[col]);
                }
            }
        }
    }
}

// ---------------- fused K+V projection + query-conv kernel (round-13, pipelined BM=64) ----------------
__global__ __launch_bounds__(256, 4)
void gqa_kvc_kernel(const float* __restrict__ Key, const float* __restrict__ Val,
                    const float* __restrict__ Query,
                    const bf16_t* __restrict__ Wtk, const bf16_t* __restrict__ Wtv,
                    const float* __restrict__ bk, const float* __restrict__ bv,
                    bf16_t* __restrict__ Kout, bf16_t* __restrict__ VtOut,
                    bf16_t* __restrict__ Qbf,
                    const float* __restrict__ cosT, const float* __restrict__ sinT) {
    __shared__ __align__(16) char smem[9216];
    bf16_t* As  = (bf16_t*)smem;                 // [64][32] = 4096 B (loop)
    bf16_t* Bs  = (bf16_t*)(smem + 4096);        // [64][32] = 4096 B (loop)
    bf16_t* VtE = (bf16_t*)smem;                 // [64][72] = 9216 B (post-loop)

    const int bx = blockIdx.x;
    const int t = threadIdx.x;

    if (bx >= 1024) {
        // ---- query fp32 -> bf16, grid-stride (512 blocks) ----
        int tid = (bx - 1024) * 256 + t;
        const int total = M_ROWS * D_MODEL / 4;
#pragma unroll 4
        for (int i = tid; i < total; i += 512 * 256) {
            float4 v = ((const float4*)Query)[i];
            bf16x4s o;
            o.x = __float2bfloat16(v.x);
            o.y = __float2bfloat16(v.y);
            o.z = __float2bfloat16(v.z);
            o.w = __float2bfloat16(v.w);
            ((bf16x4s*)Qbf)[i] = o;
        }
        return;
    }

    constexpr int K = D_MODEL;
    const int xcd = bx & 7;
    const int j   = bx >> 3;               // 0..127
    const int z   = xcd >> 2;
    const int am0 = (((xcd & 3) << 4) + (j >> 3)) * 64;
    const int bn0 = (j & 7) * 64;

    const float* A32  = z ? Val : Key;
    const bf16_t* Bt  = z ? Wtv : Wtk;
    const float* bias = z ? bv : bk;

    const int l = t & 63, w = t >> 6;
    const int lr = l & 15, lk = l >> 4;

    f32x4 acc[4];
#pragma unroll
    for (int jx = 0; jx < 4; jx++) acc[jx] = (f32x4)0.0f;

    const int sr = t >> 2;              // 0..63
    const int sc = (t & 3) * 8;
    const float*  aptr = A32 + (size_t)(am0 + sr) * K + sc;
    const bf16_t* bptr = Bt + (size_t)(bn0 + sr) * K + sc;
    bf16_t* aLds = As + sr * 32 + sc;
    bf16_t* bLds = Bs + t * 8;

    float4 pa0 = ((const float4*)aptr)[0];
    float4 pa1 = ((const float4*)aptr)[1];

    for (int it = 0; it < K / 32; ++it) {
        union { bf16x8 v; bf16_t e[8]; } u;
        u.e[0] = __float2bfloat16(pa0.x); u.e[1] = __float2bfloat16(pa0.y);
        u.e[2] = __float2bfloat16(pa0.z); u.e[3] = __float2bfloat16(pa0.w);
        u.e[4] = __float2bfloat16(pa1.x); u.e[5] = __float2bfloat16(pa1.y);
        u.e[6] = __float2bfloat16(pa1.z); u.e[7] = __float2bfloat16(pa1.w);
        *(bf16x8*)aLds = u.v;
        async_copy16(bptr + it * 32, bLds);
        __builtin_amdgcn_sched_barrier(0);
        if (it + 1 < K / 32) {
            const float* ap = aptr + (it + 1) * 32;
            pa0 = ((const float4*)ap)[0];
            pa1 = ((const float4*)ap)[1];
            __builtin_amdgcn_sched_barrier(0);
            asm volatile("s_waitcnt lgkmcnt(0) vmcnt(2)" ::: "memory");
        } else {
            asm volatile("s_waitcnt lgkmcnt(0) vmcnt(0)" ::: "memory");
        }
        __builtin_amdgcn_sched_barrier(0);
        __builtin_amdgcn_s_barrier();
        __builtin_amdgcn_sched_barrier(0);

        bf16x8 af = *(const bf16x8*)&As[(w * 16 + lr) * 32 + lk * 8];
        bf16x8 bfr[4];
#pragma unroll
        for (int ni = 0; ni < 4; ni++)
            bfr[ni] = *(const bf16x8*)&Bs[(ni * 16 + lr) * 32 + lk * 8];
#pragma unroll
        for (int ni = 0; ni < 4; ni++)
            acc[ni] = __builtin_amdgcn_mfma_f32_16x16x32_bf16(af, bfr[ni], acc[ni], 0, 0, 0);
        __builtin_amdgcn_sched_barrier(0);
        __builtin_amdgcn_s_barrier();
        __builtin_amdgcn_sched_barrier(0);
    }

    if (z == 0) {
#pragma unroll
        for (int reg = 0; reg < 4; reg++) {
            int row = am0 + w * 16 + lk * 4 + reg;
            int pos = row & (S_LEN - 1);
#pragma unroll
            for (int np = 0; np < 2; np++) {
                int jj = np * 16 + lr;
                float cs = cosT[pos * 32 + jj];
                float sn = sinT[pos * 32 + jj];
                int col1 = bn0 + np * 16 + lr;
                float x1 = acc[np][reg] + bias[col1];
                float x2 = acc[np + 2][reg] + bias[col1 + 32];
                Kout[(size_t)row * KV_D + col1]      = __float2bfloat16(x1 * cs - x2 * sn);
                Kout[(size_t)row * KV_D + col1 + 32] = __float2bfloat16(x2 * cs + x1 * sn);
            }
        }
    } else {
        __syncthreads();
#pragma unroll
        for (int ni = 0; ni < 4; ni++) {
            bf16x4s pk;
            pk.x = __float2bfloat16(acc[ni][0] + bias[bn0 + ni * 16 + lr]);
            pk.y = __float2bfloat16(acc[ni][1] + bias[bn0 + ni * 16 + lr]);
            pk.z = __float2bfloat16(acc[ni][2] + bias[bn0 + ni * 16 + lr]);
            pk.w = __float2bfloat16(acc[ni][3] + bias[bn0 + ni * 16 + lr]);
            *(bf16x4s*)&VtE[(ni * 16 + lr) * 72 + w * 16 + lk * 4] = pk;
        }
        __syncthreads();
        const int d = t & 63, w2 = t >> 6;
        const int bI = am0 >> 11;
        const int kvhI = bn0 >> 6;
        const int sl = (am0 & (S_LEN - 1)) + w2 * 16;
        bf16_t* dst = VtOut + ((size_t)(bI * N_KVH + kvhI) * HEAD_D + d) * S_LEN + sl;
        const bf16_t* src = &VtE[d * 72 + w2 * 16];
        *(bf16x8*)dst       = *(const bf16x8*)src;
        *(bf16x8*)(dst + 8) = *(const bf16x8*)(src + 8);
    }
}

// ---------------- staging (512 threads: one 16B async copy per thread) ----------------
__device__ __forceinline__ void stage_K8(const bf16_t* KB, bf16_t* dst, int kt, int t) {
    const int skey = t >> 3;                // 0..63
    const int c    = (t & 7) ^ (skey & 7);  // source chunk
    async_copy16(KB + (size_t)(kt * 64 + skey) * KV_D + c * 8, dst + t * 8);
}
__device__ __forceinline__ void stage_V8(const bf16_t* VTb, bf16_t* dst, int kt, int t) {
    const int sd = t >> 3;                  // 0..63
    const int c  = (t & 7) ^ (sd & 7);      // source chunk
    async_copy16(VTb + (size_t)sd * S_LEN + kt * 64 + c * 8, dst + t * 8);
}

// ---------------- causal GQA flash attention (swapped-QK^T, 8 waves) ----------------
// Fixed-shift softmax; denominator on the MFMA pipe (oaccS = mfma(ones, P)).
__global__ __launch_bounds__(512, 4)
void gqa_attn_kernel(const bf16_t* __restrict__ Q, const bf16_t* __restrict__ Kb,
                     const bf16_t* __restrict__ VT, bf16_t* __restrict__ Ctx) {
    __shared__ __align__(16) bf16_t Ks[2][64 * 64];    // [key][d], source-swizzled
    __shared__ __align__(16) bf16_t Vs[2][64 * 64];    // [d][key], source-swizzled
    __shared__ __align__(16) bf16_t Pw[8][16 * 72];    // per-wave P [q][key]

    const int t = threadIdx.x, l = t & 63, w = t >> 6;   // w = 0..7
    const int lr = l & 15, lk = l >> 4;

    const int flat = blockIdx.x;
    const int xcd = flat & 7, j0 = flat >> 3;            // j0: 0..63
    const int combo  = xcd * 2 + (j0 >> 5);              // b*8+kvh (16 combos)
    const int within = j0 & 31;                          // 4 heads x 8 pairs
    const int b   = combo >> 3;
    const int kvh = combo & 7;
    const int h   = kvh * 4 + (within >> 3);
    const int p   = within & 7;

    bf16x8 vones;
#pragma unroll
    for (int i = 0; i < 8; i++) vones[i] = (short)0x3F80;   // bf16 1.0

    const bf16_t* KB  = Kb + (size_t)b * S_LEN * KV_D + kvh * HEAD_D;
    const bf16_t* VTb = VT + ((size_t)(b * N_KVH + kvh) * HEAD_D) * S_LEN;

#pragma unroll
    for (int half = 0; half < 2; ++half) {
        const int qt  = half ? (NQT - 1 - p) : p;
        const int q0w = qt * 128 + w * 16;
        const int qg  = q0w + lr;                       // this lane's q row

        bf16x8 qf[2];
        {
            const bf16_t* qrow = Q + ((size_t)(b * S_LEN + qg)) * D_MODEL + h * HEAD_D;
            qf[0] = *(const bf16x8*)(qrow + lk * 8);
            qf[1] = *(const bf16x8*)(qrow + 32 + lk * 8);
        }

        f32x4 oaccT[4];                                 // O^T: d = df*16+lk*4+r, q = lr
        f32x4 oaccS = (f32x4)0.0f;                      // denominator
#pragma unroll
        for (int df = 0; df < 4; df++) oaccT[df] = (f32x4)0.0f;

        const int nkt = 2 * qt + 2;

        stage_K8(KB, Ks[0], 0, t);
        stage_V8(VTb, Vs[0], 0, t);
        __syncthreads();

        int cur = 0;
        for (int kt = 0; kt < nkt; ++kt) {
            const bool pre = (kt + 1 < nkt);
            if (pre) {
                stage_K8(KB, Ks[cur ^ 1], kt + 1, t);
                stage_V8(VTb, Vs[cur ^ 1], kt + 1, t);
            }

            if (kt * 64 <= q0w + 15) {                  // wave-uniform causal skip
                const bool diag = (kt * 64 + 63 > q0w);

                // ---- S^T = mfma(K, Q) ----
                f32x4 sfrT[4];
#pragma unroll
                for (int ni = 0; ni < 4; ni++) sfrT[ni] = (f32x4)0.0f;
                __builtin_amdgcn_s_setprio(1);
#pragma unroll
                for (int ni = 0; ni < 4; ni++)
#pragma unroll
                    for (int ks = 0; ks < 2; ks++) {
                        bf16x8 kf = *(const bf16x8*)&Ks[cur][(ni * 16 + lr) * 64 +
                                        ((ks * 32 + lk * 8) ^ ((lr & 7) << 3))];
                        sfrT[ni] = __builtin_amdgcn_mfma_f32_16x16x32_bf16(kf, qf[ks],
                                                                           sfrT[ni], 0, 0, 0);
                    }
                __builtin_amdgcn_s_setprio(0);

                // ---- mask + direct exp2 ----
#pragma unroll
                for (int ni = 0; ni < 4; ni++) {
                    float sc0 = sfrT[ni][0], sc1 = sfrT[ni][1];
                    float sc2 = sfrT[ni][2], sc3 = sfrT[ni][3];
                    if (diag) {
                        int kbase = kt * 64 + ni * 16 + lk * 4;
                        if (kbase + 0 > qg) sc0 = -1e30f;
                        if (kbase + 1 > qg) sc1 = -1e30f;
                        if (kbase + 2 > qg) sc2 = -1e30f;
                        if (kbase + 3 > qg) sc3 = -1e30f;
                    }
                    bf16x4s pk;
                    pk.x = __float2bfloat16(exp2f(sc0));
                    pk.y = __float2bfloat16(exp2f(sc1));
                    pk.z = __float2bfloat16(exp2f(sc2));
                    pk.w = __float2bfloat16(exp2f(sc3));
                    *(bf16x4s*)&Pw[w][lr * 72 + ni * 16 + lk * 4] = pk;
                }

                // ---- O^T += mfma(V^T, P^T); l += mfma(ones, P^T) ----
                __builtin_amdgcn_s_setprio(1);
#pragma unroll
                for (int ks = 0; ks < 2; ks++) {
                    bf16x8 pf = *(const bf16x8*)&Pw[w][lr * 72 + ks * 32 + lk * 8];
                    oaccS = __builtin_amdgcn_mfma_f32_16x16x32_bf16(vones, pf, oaccS, 0, 0, 0);
#pragma unroll
                    for (int df = 0; df < 4; df++) {
                        bf16x8 vf = *(const bf16x8*)&Vs[cur][(df * 16 + lr) * 64 +
                                        ((ks * 32 + lk * 8) ^ ((lr & 7) << 3))];
                        oaccT[df] = __builtin_amdgcn_mfma_f32_16x16x32_bf16(vf, pf,
                                            oaccT[df], 0, 0, 0);
                    }
                }
                __builtin_amdgcn_s_setprio(0);
            }

            __syncthreads();
            cur ^= 1;
        }

        // ---- normalize + write ctx ----
        {
            float inv = 1.0f / oaccS[0];
            bf16_t* crow = Ctx + ((size_t)(b * S_LEN + qg)) * D_MODEL + h * HEAD_D;
#pragma unroll
            for (int df = 0; df < 4; df++) {
                bf16x4s ov;
                ov.x = __float2bfloat16(oaccT[df][0] * inv);
                ov.y = __float2bfloat16(oaccT[df][1] * inv);
                ov.z = __float2bfloat16(oaccT[df][2] * inv);
                ov.w = __float2bfloat16(oaccT[df][3] * inv);
                *(bf16x4s*)(crow + df * 16 + lk * 4) = ov;
            }
        }
    }
}

extern "C" void kernel_launch(void* const* d_in, const int* in_sizes, int n_in,
                              void* d_out, int out_size, void* d_ws, size_t ws_size,
                              hipStream_t stream) {
    const float* query = (const float*)d_in[0];
    const float* key_  = (const float*)d_in[1];
    const float* value = (const float*)d_in[2];
    const float* w_q = (const float*)d_in[3];
    const float* b_q = (const float*)d_in[4];
    const float* w_k = (const float*)d_in[5];
    const float* b_k = (const float*)d_in[6];
    const float* w_v = (const float*)d_in[7];
    const float* b_v = (const float*)d_in[8];
    const float* w_o = (const float*)d_in[9];
    const float* b_o = (const float*)d_in[10];
    float* out = (float*)d_out;

    char* ws = (char*)d_ws;
    bf16_t* Abuf = (bf16_t*)(ws);                       // 16MB (Q bf16, reused as ctx)
    bf16_t* qb   = (bf16_t*)(ws + (size_t)(16 << 20));  // 16MB
    bf16_t* kb   = (bf16_t*)(ws + (size_t)(32 << 20));  // 4MB
    bf16_t* vt   = (bf16_t*)(ws + (size_t)(36 << 20));  // 4MB (transposed V)
    bf16_t* wtq  = (bf16_t*)(ws + (size_t)(40 << 20));  // 8MB
    bf16_t* wtk  = (bf16_t*)(ws + (size_t)(48 << 20));  // 2MB
    bf16_t* wtv  = (bf16_t*)(ws + (size_t)(50 << 20));  // 2MB
    bf16_t* wto  = (bf16_t*)(ws + (size_t)(52 << 20));  // 8MB
    float* cosT  = (float*)(ws + (size_t)(60 << 20));   // 256KB
    float* sinT  = (float*)(ws + (size_t)(60 << 20) + (256 << 10));

    // weight transposes + RoPE table, one dispatch
    wt_conv_all_kernel<<<dim3(161, 64), 256, 0, stream>>>(w_q, w_k, w_v, w_o,
                                                          wtq, wtk, wtv, wto, cosT, sinT);

    // K + V projections (pipelined, BM=64) + query conv, one dispatch
    gqa_kvc_kernel<<<1536, 256, 0, stream>>>(key_, value, query, wtk, wtv,
                                             b_k, b_v, kb, vt, Abuf, cosT, sinT);

    // Q projection (+RoPE, QK_SCALE): 1D XCD-tiled grid
    gqa_gemm_kernel<1, 0, 1><<<512, 256, 0, stream>>>(
        Abuf, wtq, b_q, qb, M_ROWS, D_MODEL, D_MODEL, cosT, sinT);

    // Attention -> ctx (Abuf); 8-wave blocks, XCD decode, MFMA-denominator softmax
    gqa_attn_kernel<<<512, 512, 0, stream>>>(qb, kb, vt, Abuf);

    // Output projection -> fp32 d_out: 1D XCD-tiled grid
    gqa_gemm_kernel<0, 1, 0><<<512, 256, 0, stream>>>(
        Abuf, wto, b_o, out, M_ROWS, D_MODEL, D_MODEL, cosT, sinT);
}

// Round 16
// 203.489 us; speedup vs baseline: 1.1051x; 1.0379x over previous
//
#include <hip/hip_runtime.h>
#include <hip/hip_bf16.h>

typedef __hip_bfloat16 bf16_t;
typedef __attribute__((ext_vector_type(8))) short bf16x8;
typedef __attribute__((ext_vector_type(4))) float f32x4;

#define S_LEN   2048
#define D_MODEL 2048
#define N_QH    32
#define N_KVH   8
#define HEAD_D  64
#define KV_D    512
#define M_ROWS  4096
#define QK_SCALE (0.125f * 1.44269504088896340736f)   // att_scale * log2(e), folded into Q
#define NQT     16              // q-tiles of 128 rows

struct __align__(8) bf16x4s { bf16_t x, y, z, w; };

// ---------------- prep: weight transposes + RoPE table + q/k/v fp32->bf16 ----------------
// 1D grid 11840: [0,10240) wt tiles; [10240,10304) rope; [10304,11840) conv.
__global__ void prep_kernel(const float* __restrict__ wq, const float* __restrict__ wk,
                            const float* __restrict__ wv, const float* __restrict__ wo,
                            bf16_t* __restrict__ tq, bf16_t* __restrict__ tk,
                            bf16_t* __restrict__ tv, bf16_t* __restrict__ to,
                            const float* __restrict__ query, const float* __restrict__ key_,
                            const float* __restrict__ value,
                            bf16_t* __restrict__ qbf, bf16_t* __restrict__ kbf,
                            bf16_t* __restrict__ vbf,
                            float* __restrict__ cosT, float* __restrict__ sinT) {
    const int bx = blockIdx.x, t = threadIdx.x;
    if (bx < 10240) {
        __shared__ float tile[32][33];
        const float* W; bf16_t* Wt; int N, nb, kt;
        if (bx < 4096)      { W = wq; Wt = tq; N = D_MODEL; nb = bx & 63;          kt = bx >> 6; }
        else if (bx < 5120) { int i = bx - 4096; W = wk; Wt = tk; N = KV_D; nb = i & 15; kt = i >> 4; }
        else if (bx < 6144) { int i = bx - 5120; W = wv; Wt = tv; N = KV_D; nb = i & 15; kt = i >> 4; }
        else                { int i = bx - 6144; W = wo; Wt = to; N = D_MODEL; nb = i & 63; kt = i >> 6; }
        const int K = D_MODEL;
        int n0 = nb * 32, k0 = kt * 32;
        int tx = t & 31, ty = t >> 5;   // 32 x 8
#pragma unroll
        for (int i = 0; i < 4; i++) {
            int r = ty + i * 8;
            tile[r][tx] = W[(size_t)(k0 + r) * N + n0 + tx];
        }
        __syncthreads();
#pragma unroll
        for (int i = 0; i < 4; i++) {
            int r = ty + i * 8;
            Wt[(size_t)(n0 + r) * K + k0 + tx] = __float2bfloat16(tile[tx][r]);
        }
        return;
    }
    if (bx < 10304) {
        int blk = bx - 10240;
        int j = t & 31;
        double invf = pow(10000.0, -(double)(2 * j) / 64.0);
#pragma unroll
        for (int i = 0; i < 4; i++) {
            int pos = blk * 32 + i * 8 + (t >> 5);
            double a = (double)pos * invf;
            cosT[pos * 32 + j] = (float)cos(a);
            sinT[pos * 32 + j] = (float)sin(a);
        }
        return;
    }
    // conv q/k/v: grid-stride over 3 x 2M float4
    const int per = M_ROWS * D_MODEL / 4;
    int tid = (bx - 10304) * 256 + t;
    for (int i = tid; i < 3 * per; i += 1536 * 256) {
        const float* src; bf16_t* dst; int off;
        if (i < per)          { src = query; dst = qbf; off = i; }
        else if (i < 2 * per) { src = key_;  dst = kbf; off = i - per; }
        else                  { src = value; dst = vbf; off = i - 2 * per; }
        float4 v = ((const float4*)src)[off];
        bf16x4s o;
        o.x = __float2bfloat16(v.x);
        o.y = __float2bfloat16(v.y);
        o.z = __float2bfloat16(v.z);
        o.w = __float2bfloat16(v.w);
        ((bf16x4s*)dst)[off] = o;
    }
}

// ---------------- async 16B global->LDS ----------------
__device__ __forceinline__ void async_copy16(const bf16_t* g, bf16_t* l) {
    __builtin_amdgcn_global_load_lds((const __attribute__((address_space(1))) void*)g,
                                     (__attribute__((address_space(3))) void*)l, 16, 0, 0);
}

// ---------------- O-projection GEMM (unchanged): 128x128, BK=64, XCD-tiled ----------------
template <int ROPE, int OUTF32, int QSCALE>
__global__ __launch_bounds__(256, 2)
void gqa_gemm_kernel(const bf16_t* __restrict__ A, const bf16_t* __restrict__ Bt,
                     const float* __restrict__ bias, void* __restrict__ Cout,
                     int M, int N, int K,
                     const float* __restrict__ cosT, const float* __restrict__ sinT) {
    __shared__ __align__(16) bf16_t As[128 * 64];
    __shared__ __align__(16) bf16_t Bs[128 * 64];

    const int t = threadIdx.x;
    const int bx = blockIdx.x;
    const int xcd = bx & 7, j = bx >> 3;
    const int am0 = (((xcd >> 1) << 3) + (j >> 3)) * 128;
    const int bn0 = (((xcd & 1) << 3) + (j & 7)) * 128;

    const int l = t & 63, w = t >> 6;
    const int wr = w >> 1, wc = w & 1;
    const int lr = l & 15, lk = l >> 4;

    f32x4 acc[4][4];
#pragma unroll
    for (int i = 0; i < 4; i++)
#pragma unroll
        for (int jx = 0; jx < 4; jx++) acc[i][jx] = (f32x4)0.0f;

    const int r0 = t >> 3;
    const int c  = (t & 7) ^ (r0 & 7);
    const bf16_t* aptr = A + (size_t)(am0 + r0) * K + c * 8;
    const bf16_t* bptr = Bt + (size_t)(bn0 + r0) * K + c * 8;
    bf16_t* aLds = As + r0 * 64 + (t & 7) * 8;
    bf16_t* bLds = Bs + r0 * 64 + (t & 7) * 8;

    for (int k0 = 0; k0 < K; k0 += 64) {
#pragma unroll
        for (int s = 0; s < 4; ++s) {
            async_copy16(aptr + (size_t)(s * 32) * K + k0, aLds + s * 2048);
            async_copy16(bptr + (size_t)(s * 32) * K + k0, bLds + s * 2048);
        }
        __syncthreads();

        bf16x8 af[4][2], bfr[4][2];
#pragma unroll
        for (int mi = 0; mi < 4; mi++)
#pragma unroll
            for (int ks = 0; ks < 2; ks++)
                af[mi][ks] = *(const bf16x8*)&As[(wr * 64 + mi * 16 + lr) * 64 +
                                 ((ks * 32 + lk * 8) ^ ((lr & 7) << 3))];
#pragma unroll
        for (int ni = 0; ni < 4; ni++)
#pragma unroll
            for (int ks = 0; ks < 2; ks++)
                bfr[ni][ks] = *(const bf16x8*)&Bs[(wc * 64 + ni * 16 + lr) * 64 +
                                  ((ks * 32 + lk * 8) ^ ((lr & 7) << 3))];
#pragma unroll
        for (int mi = 0; mi < 4; mi++)
#pragma unroll
            for (int ni = 0; ni < 4; ni++)
#pragma unroll
                for (int ks = 0; ks < 2; ks++)
                    acc[mi][ni] = __builtin_amdgcn_mfma_f32_16x16x32_bf16(
                        af[mi][ks], bfr[ni][ks], acc[mi][ni], 0, 0, 0);
        __syncthreads();
    }

#pragma unroll
    for (int mi = 0; mi < 4; mi++) {
#pragma unroll
        for (int reg = 0; reg < 4; reg++) {
            int row = am0 + wr * 64 + mi * 16 + lk * 4 + reg;
            if (OUTF32) {
                float* out = (float*)Cout;
#pragma unroll
                for (int ni = 0; ni < 4; ni++) {
                    int col = bn0 + wc * 64 + ni * 16 + lr;
                    out[(size_t)row * N + col] = acc[mi][ni][reg] + bias[col];
                }
            } else if (ROPE) {
                bf16_t* out = (bf16_t*)Cout;
                int pos = row & (S_LEN - 1);
#pragma unroll
                for (int np = 0; np < 2; np++) {
                    int jj = np * 16 + lr;
                    float cs = cosT[pos * 32 + jj];
                    float sn = sinT[pos * 32 + jj];
                    int col1 = bn0 + wc * 64 + np * 16 + lr;
                    float x1 = acc[mi][np][reg] + bias[col1];
                    float x2 = acc[mi][np + 2][reg] + bias[col1 + 32];
                    float o1 = x1 * cs - x2 * sn;
                    float o2 = x2 * cs + x1 * sn;
                    if (QSCALE) { o1 *= QK_SCALE; o2 *= QK_SCALE; }
                    out[(size_t)row * N + col1]      = __float2bfloat16(o1);
                    out[(size_t)row * N + col1 + 32] = __float2bfloat16(o2);
                }
            } else {
                bf16_t* out = (bf16_t*)Cout;
#pragma unroll
                for (int ni = 0; ni < 4; ni++) {
                    int col = bn0 + wc * 64 + ni * 16 + lr;
                    out[(size_t)row * N + col] =
                        __float2bfloat16(acc[mi][ni][reg] + bias[col]);
                }
            }
        }
    }
}

// ---------------- fused Q+K+V projection GEMM: one inner loop, three epilogues ----------------
// 768 blocks: [0,512) Q (XCD-tiled, ROPE+QSCALE -> qb); [512,640) K (ROPE -> kb);
// [640,768) V (LDS-transpose -> vt). All share the identical 128x128 BK=64 loop.
__global__ __launch_bounds__(256, 2)
void gqa_qkv_kernel(const bf16_t* __restrict__ Qbf, const bf16_t* __restrict__ Kbf,
                    const bf16_t* __restrict__ Vbf,
                    const bf16_t* __restrict__ Wtq, const bf16_t* __restrict__ Wtk,
                    const bf16_t* __restrict__ Wtv,
                    const float* __restrict__ bq, const float* __restrict__ bk,
                    const float* __restrict__ bv,
                    bf16_t* __restrict__ Qout, bf16_t* __restrict__ Kout,
                    bf16_t* __restrict__ VtOut,
                    const float* __restrict__ cosT, const float* __restrict__ sinT) {
    __shared__ __align__(16) char smem[128 * 140 * 2];   // 35840 B
    bf16_t* As = (bf16_t*)smem;                          // [128*64] loop
    bf16_t* Bs = (bf16_t*)(smem + 16384);                // [128*64] loop
    bf16_t* TT = (bf16_t*)smem;                          // [128][140] V epilogue

    const int t = threadIdx.x, bx = blockIdx.x;
    constexpr int K = D_MODEL;

    int am0, bn0, mode;
    const bf16_t *A, *Bt; const float* bias;
    if (bx < 512) {
        int xcd = bx & 7, j = bx >> 3;
        am0 = (((xcd >> 1) << 3) + (j >> 3)) * 128;
        bn0 = (((xcd & 1) << 3) + (j & 7)) * 128;
        A = Qbf; Bt = Wtq; bias = bq; mode = 0;
    } else {
        int idx = bx - 512;
        int z = idx >> 7;                  // 0:K 1:V
        int xcd = idx & 7, jj = (idx & 127) >> 3;   // 0..15
        am0 = (xcd * 4 + (jj & 3)) * 128;
        bn0 = (jj >> 2) * 128;
        A = z ? Vbf : Kbf; Bt = z ? Wtv : Wtk; bias = z ? bv : bk; mode = z ? 2 : 1;
    }

    const int l = t & 63, w = t >> 6;
    const int wr = w >> 1, wc = w & 1;
    const int lr = l & 15, lk = l >> 4;

    f32x4 acc[4][4];
#pragma unroll
    for (int i = 0; i < 4; i++)
#pragma unroll
        for (int jx = 0; jx < 4; jx++) acc[i][jx] = (f32x4)0.0f;

    const int r0 = t >> 3;
    const int c  = (t & 7) ^ (r0 & 7);
    const bf16_t* aptr = A + (size_t)(am0 + r0) * K + c * 8;
    const bf16_t* bptr = Bt + (size_t)(bn0 + r0) * K + c * 8;
    bf16_t* aLds = As + r0 * 64 + (t & 7) * 8;
    bf16_t* bLds = Bs + r0 * 64 + (t & 7) * 8;

    for (int k0 = 0; k0 < K; k0 += 64) {
#pragma unroll
        for (int s = 0; s < 4; ++s) {
            async_copy16(aptr + (size_t)(s * 32) * K + k0, aLds + s * 2048);
            async_copy16(bptr + (size_t)(s * 32) * K + k0, bLds + s * 2048);
        }
        __syncthreads();

        bf16x8 af[4][2], bfr[4][2];
#pragma unroll
        for (int mi = 0; mi < 4; mi++)
#pragma unroll
            for (int ks = 0; ks < 2; ks++)
                af[mi][ks] = *(const bf16x8*)&As[(wr * 64 + mi * 16 + lr) * 64 +
                                 ((ks * 32 + lk * 8) ^ ((lr & 7) << 3))];
#pragma unroll
        for (int ni = 0; ni < 4; ni++)
#pragma unroll
            for (int ks = 0; ks < 2; ks++)
                bfr[ni][ks] = *(const bf16x8*)&Bs[(wc * 64 + ni * 16 + lr) * 64 +
                                  ((ks * 32 + lk * 8) ^ ((lr & 7) << 3))];
#pragma unroll
        for (int mi = 0; mi < 4; mi++)
#pragma unroll
            for (int ni = 0; ni < 4; ni++)
#pragma unroll
                for (int ks = 0; ks < 2; ks++)
                    acc[mi][ni] = __builtin_amdgcn_mfma_f32_16x16x32_bf16(
                        af[mi][ks], bfr[ni][ks], acc[mi][ni], 0, 0, 0);
        __syncthreads();
    }

    if (mode == 2) {
        // V: bias + transpose via LDS [128 col][140], then contiguous writes to vt
#pragma unroll
        for (int mi = 0; mi < 4; mi++)
#pragma unroll
            for (int ni = 0; ni < 4; ni++) {
                int colL = wc * 64 + ni * 16 + lr;
                float bz = bias[bn0 + colL];
                bf16x4s pk;
                pk.x = __float2bfloat16(acc[mi][ni][0] + bz);
                pk.y = __float2bfloat16(acc[mi][ni][1] + bz);
                pk.z = __float2bfloat16(acc[mi][ni][2] + bz);
                pk.w = __float2bfloat16(acc[mi][ni][3] + bz);
                *(bf16x4s*)&TT[colL * 140 + wr * 64 + mi * 16 + lk * 4] = pk;
            }
        __syncthreads();
        const int colL = t >> 1, s0 = (t & 1) * 64;
        const int cg = bn0 + colL;
        const int bI = am0 >> 11;
        bf16_t* dst = VtOut + ((size_t)(bI * N_KVH + (cg >> 6)) * HEAD_D + (cg & 63)) * S_LEN
                      + (am0 & (S_LEN - 1)) + s0;
        const bf16_t* src = &TT[colL * 140 + s0];
#pragma unroll
        for (int i = 0; i < 8; i++)
            *(bf16x8*)(dst + i * 8) = *(const bf16x8*)(src + i * 8);
        return;
    }

    // Q / K: RoPE epilogue (Q additionally scaled by QK_SCALE)
    const int N = (mode == 0) ? D_MODEL : KV_D;
    bf16_t* out = (mode == 0) ? Qout : Kout;
    const float qs = (mode == 0) ? QK_SCALE : 1.0f;
#pragma unroll
    for (int mi = 0; mi < 4; mi++)
#pragma unroll
        for (int reg = 0; reg < 4; reg++) {
            int row = am0 + wr * 64 + mi * 16 + lk * 4 + reg;
            int pos = row & (S_LEN - 1);
#pragma unroll
            for (int np = 0; np < 2; np++) {
                int jj = np * 16 + lr;
                float cs = cosT[pos * 32 + jj];
                float sn = sinT[pos * 32 + jj];
                int col1 = bn0 + wc * 64 + np * 16 + lr;
                float x1 = acc[mi][np][reg] + bias[col1];
                float x2 = acc[mi][np + 2][reg] + bias[col1 + 32];
                out[(size_t)row * N + col1]      = __float2bfloat16((x1 * cs - x2 * sn) * qs);
                out[(size_t)row * N + col1 + 32] = __float2bfloat16((x2 * cs + x1 * sn) * qs);
            }
        }
}

// ---------------- staging (512 threads: one 16B async copy per thread) ----------------
__device__ __forceinline__ void stage_K8(const bf16_t* KB, bf16_t* dst, int kt, int t) {
    const int skey = t >> 3;
    const int c    = (t & 7) ^ (skey & 7);
    async_copy16(KB + (size_t)(kt * 64 + skey) * KV_D + c * 8, dst + t * 8);
}
__device__ __forceinline__ void stage_V8(const bf16_t* VTb, bf16_t* dst, int kt, int t) {
    const int sd = t >> 3;
    const int c  = (t & 7) ^ (sd & 7);
    async_copy16(VTb + (size_t)sd * S_LEN + kt * 64 + c * 8, dst + t * 8);
}

// ---------------- causal GQA flash attention (unchanged from round 15) ----------------
__global__ __launch_bounds__(512, 4)
void gqa_attn_kernel(const bf16_t* __restrict__ Q, const bf16_t* __restrict__ Kb,
                     const bf16_t* __restrict__ VT, bf16_t* __restrict__ Ctx) {
    __shared__ __align__(16) bf16_t Ks[2][64 * 64];
    __shared__ __align__(16) bf16_t Vs[2][64 * 64];
    __shared__ __align__(16) bf16_t Pw[8][16 * 72];

    const int t = threadIdx.x, l = t & 63, w = t >> 6;
    const int lr = l & 15, lk = l >> 4;

    const int flat = blockIdx.x;
    const int xcd = flat & 7, j0 = flat >> 3;
    const int combo  = xcd * 2 + (j0 >> 5);
    const int within = j0 & 31;
    const int b   = combo >> 3;
    const int kvh = combo & 7;
    const int h   = kvh * 4 + (within >> 3);
    const int p   = within & 7;

    bf16x8 vones;
#pragma unroll
    for (int i = 0; i < 8; i++) vones[i] = (short)0x3F80;

    const bf16_t* KB  = Kb + (size_t)b * S_LEN * KV_D + kvh * HEAD_D;
    const bf16_t* VTb = VT + ((size_t)(b * N_KVH + kvh) * HEAD_D) * S_LEN;

#pragma unroll
    for (int half = 0; half < 2; ++half) {
        const int qt  = half ? (NQT - 1 - p) : p;
        const int q0w = qt * 128 + w * 16;
        const int qg  = q0w + lr;

        bf16x8 qf[2];
        {
            const bf16_t* qrow = Q + ((size_t)(b * S_LEN + qg)) * D_MODEL + h * HEAD_D;
            qf[0] = *(const bf16x8*)(qrow + lk * 8);
            qf[1] = *(const bf16x8*)(qrow + 32 + lk * 8);
        }

        f32x4 oaccT[4];
        f32x4 oaccS = (f32x4)0.0f;
#pragma unroll
        for (int df = 0; df < 4; df++) oaccT[df] = (f32x4)0.0f;

        const int nkt = 2 * qt + 2;

        stage_K8(KB, Ks[0], 0, t);
        stage_V8(VTb, Vs[0], 0, t);
        __syncthreads();

        int cur = 0;
        for (int kt = 0; kt < nkt; ++kt) {
            const bool pre = (kt + 1 < nkt);
            if (pre) {
                stage_K8(KB, Ks[cur ^ 1], kt + 1, t);
                stage_V8(VTb, Vs[cur ^ 1], kt + 1, t);
            }

            if (kt * 64 <= q0w + 15) {
                const bool diag = (kt * 64 + 63 > q0w);

                f32x4 sfrT[4];
#pragma unroll
                for (int ni = 0; ni < 4; ni++) sfrT[ni] = (f32x4)0.0f;
                __builtin_amdgcn_s_setprio(1);
#pragma unroll
                for (int ni = 0; ni < 4; ni++)
#pragma unroll
                    for (int ks = 0; ks < 2; ks++) {
                        bf16x8 kf = *(const bf16x8*)&Ks[cur][(ni * 16 + lr) * 64 +
                                        ((ks * 32 + lk * 8) ^ ((lr & 7) << 3))];
                        sfrT[ni] = __builtin_amdgcn_mfma_f32_16x16x32_bf16(kf, qf[ks],
                                                                           sfrT[ni], 0, 0, 0);
                    }
                __builtin_amdgcn_s_setprio(0);

#pragma unroll
                for (int ni = 0; ni < 4; ni++) {
                    float sc0 = sfrT[ni][0], sc1 = sfrT[ni][1];
                    float sc2 = sfrT[ni][2], sc3 = sfrT[ni][3];
                    if (diag) {
                        int kbase = kt * 64 + ni * 16 + lk * 4;
                        if (kbase + 0 > qg) sc0 = -1e30f;
                        if (kbase + 1 > qg) sc1 = -1e30f;
                        if (kbase + 2 > qg) sc2 = -1e30f;
                        if (kbase + 3 > qg) sc3 = -1e30f;
                    }
                    bf16x4s pk;
                    pk.x = __float2bfloat16(exp2f(sc0));
                    pk.y = __float2bfloat16(exp2f(sc1));
                    pk.z = __float2bfloat16(exp2f(sc2));
                    pk.w = __float2bfloat16(exp2f(sc3));
                    *(bf16x4s*)&Pw[w][lr * 72 + ni * 16 + lk * 4] = pk;
                }

                __builtin_amdgcn_s_setprio(1);
#pragma unroll
                for (int ks = 0; ks < 2; ks++) {
                    bf16x8 pf = *(const bf16x8*)&Pw[w][lr * 72 + ks * 32 + lk * 8];
                    oaccS = __builtin_amdgcn_mfma_f32_16x16x32_bf16(vones, pf, oaccS, 0, 0, 0);
#pragma unroll
                    for (int df = 0; df < 4; df++) {
                        bf16x8 vf = *(const bf16x8*)&Vs[cur][(df * 16 + lr) * 64 +
                                        ((ks * 32 + lk * 8) ^ ((lr & 7) << 3))];
                        oaccT[df] = __builtin_amdgcn_mfma_f32_16x16x32_bf16(vf, pf,
                                            oaccT[df], 0, 0, 0);
                    }
                }
                __builtin_amdgcn_s_setprio(0);
            }

            __syncthreads();
            cur ^= 1;
        }

        {
            float inv = 1.0f / oaccS[0];
            bf16_t* crow = Ctx + ((size_t)(b * S_LEN + qg)) * D_MODEL + h * HEAD_D;
#pragma unroll
            for (int df = 0; df < 4; df++) {
                bf16x4s ov;
                ov.x = __float2bfloat16(oaccT[df][0] * inv);
                ov.y = __float2bfloat16(oaccT[df][1] * inv);
                ov.z = __float2bfloat16(oaccT[df][2] * inv);
                ov.w = __float2bfloat16(oaccT[df][3] * inv);
                *(bf16x4s*)(crow + df * 16 + lk * 4) = ov;
            }
        }
    }
}

extern "C" void kernel_launch(void* const* d_in, const int* in_sizes, int n_in,
                              void* d_out, int out_size, void* d_ws, size_t ws_size,
                              hipStream_t stream) {
    const float* query = (const float*)d_in[0];
    const float* key_  = (const float*)d_in[1];
    const float* value = (const float*)d_in[2];
    const float* w_q = (const float*)d_in[3];
    const float* b_q = (const float*)d_in[4];
    const float* w_k = (const float*)d_in[5];
    const float* b_k = (const float*)d_in[6];
    const float* w_v = (const float*)d_in[7];
    const float* b_v = (const float*)d_in[8];
    const float* w_o = (const float*)d_in[9];
    const float* b_o = (const float*)d_in[10];
    float* out = (float*)d_out;

    char* ws = (char*)d_ws;
    bf16_t* qbf  = (bf16_t*)(ws);                       // 16MB (query bf16; reused as ctx)
    bf16_t* qb   = (bf16_t*)(ws + (size_t)(16 << 20));  // 16MB
    bf16_t* kb   = (bf16_t*)(ws + (size_t)(32 << 20));  // 4MB
    bf16_t* vt   = (bf16_t*)(ws + (size_t)(36 << 20));  // 4MB (transposed V)
    bf16_t* wtq  = (bf16_t*)(ws + (size_t)(40 << 20));  // 8MB
    bf16_t* wtk  = (bf16_t*)(ws + (size_t)(48 << 20));  // 2MB
    bf16_t* wtv  = (bf16_t*)(ws + (size_t)(50 << 20));  // 2MB
    bf16_t* wto  = (bf16_t*)(ws + (size_t)(52 << 20));  // 8MB
    float* cosT  = (float*)(ws + (size_t)(60 << 20));   // 256KB
    float* sinT  = (float*)(ws + (size_t)(60 << 20) + (256 << 10));
    bf16_t* kbf  = (bf16_t*)(ws + (size_t)(61 << 20));  // 16MB (key bf16)
    bf16_t* vbf  = (bf16_t*)(ws + (size_t)(77 << 20));  // 16MB (value bf16)

    // 1) weight transposes + RoPE table + q/k/v conversion
    prep_kernel<<<11840, 256, 0, stream>>>(w_q, w_k, w_v, w_o, wtq, wtk, wtv, wto,
                                           query, key_, value, qbf, kbf, vbf, cosT, sinT);

    // 2) fused Q+K+V projection GEMM (one loop shape, three epilogues)
    gqa_qkv_kernel<<<768, 256, 0, stream>>>(qbf, kbf, vbf, wtq, wtk, wtv,
                                            b_q, b_k, b_v, qb, kb, vt, cosT, sinT);

    // 3) attention -> ctx (reuses qbf buffer)
    gqa_attn_kernel<<<512, 512, 0, stream>>>(qb, kb, vt, qbf);

    // 4) output projection -> fp32 d_out
    gqa_gemm_kernel<0, 1, 0><<<512, 256, 0, stream>>>(
        qbf, wto, b_o, out, M_ROWS, D_MODEL, D_MODEL, cosT, sinT);
}